// Round 14
// baseline (62.389 us; speedup 1.0000x reference)
//
#include <hip/hip_runtime.h>

#define Bn 8
#define Nn 2048
#define Dn 128
#define OUTn 128

typedef __attribute__((ext_vector_type(8))) short bf16x8;     // MFMA A/B operand (8 bf16)
typedef __attribute__((ext_vector_type(8))) unsigned short ushort8;
typedef __attribute__((ext_vector_type(4))) float f32x4;      // MFMA C/D
typedef __attribute__((ext_vector_type(4))) int int4v;
typedef __attribute__((ext_vector_type(4))) unsigned int uint4v;
typedef __attribute__((ext_vector_type(4))) float float4v;

__device__ __forceinline__ unsigned short f2bf(float f) {
  unsigned int u = __builtin_bit_cast(unsigned int, f);
  u += 0x7FFFu + ((u >> 16) & 1u);   // round-to-nearest-even
  return (unsigned short)(u >> 16);
}

// ---------------- prep: transpose input + transpose W ----------------
__global__ __launch_bounds__(256) void gcn_prep(const float* __restrict__ in,
                                                const float* __restrict__ W,
                                                unsigned short* __restrict__ inT,
                                                unsigned short* __restrict__ WT) {
  const int tid = threadIdx.x;
  if (blockIdx.x >= 256) {
    int gid = (blockIdx.x - 256) * 256 + tid;    // 0..32767
    int j = gid >> 8, k = gid & 255;             // WT[j][k] = W[k][j]
    WT[gid] = f2bf(W[k * OUTn + j]);
    return;
  }
  const int b = blockIdx.x >> 5;
  const int n0 = (blockIdx.x & 31) * 64;
  __shared__ __attribute__((aligned(16))) unsigned short lds[64][130];
  #pragma unroll
  for (int c = 0; c < 32; ++c) {
    int e = tid + c * 256;
    int i = e >> 7, d = e & 127;
    lds[i][d] = f2bf(in[((size_t)(b * Nn + n0 + i)) * Dn + d]);
  }
  __syncthreads();
  #pragma unroll
  for (int c = 0; c < 4; ++c) {
    int ch = tid + c * 256;
    int d = ch >> 3, g = (ch & 7) * 8;
    ushort8 v;
    #pragma unroll
    for (int e = 0; e < 8; ++e) v[e] = lds[g + e][d];
    *(ushort8*)(inT + ((size_t)(b * Dn + d)) * Nn + n0 + g) = v;
  }
}

// ---------------- main: A direct-to-VGPR (plain loads, phase-pinned), B DMA --
// 256 blocks x 512 threads (8 waves). Block = 64 rows of one batch, BK=64.
// A-frags loaded from adj into registers with PLAIN int4v loads; the phase
// structure (asm s_waitcnt vmcnt(N) with "memory" clobber + sched_barrier(0)
// at every WAITBAR) pins each STAGE's loads inside its phase, so the
// compiler cannot sink them next to consumers (the R6/R7 failure). Its own
// auto-waitcnt before the A-consume is a counted wait (~vmcnt(14)), not a
// drain. 3-deep A-reg rotation mirrors the 3-buffer B LDS rotation.
// Per STAGE: 4 A-loads + 2 B-DMA = 6 vmem ops -> WAITBAR(6) = tile kt fully
// landed, kt+1 in flight. LDS carries ONLY B (48 KB): LDS/iter 128->80 KB.
// A converted at consume (adj in {0,1}: bf16 = v*0x3F80); degree free.
union SMem {
  unsigned short Bs[3][128][64];       // 48 KB (swizzled content, linear layout)
  struct {
    unsigned short aggl[64][136];      // bf16 agg for GEMM2 A-frags
    float rowsum[64][2];
    float degs[64];
  } e;
};

#define STAGE(ab, cur, kt) do {                                                \
    ab[0] = *(const int4v*)(pA);                                               \
    ab[1] = *(const int4v*)(pA + 4);                                           \
    ab[2] = *(const int4v*)(pA + 32);                                          \
    ab[3] = *(const int4v*)(pA + 36);                                          \
    pA += 64;                          /* advance one K-tile (64 ints) */      \
    _Pragma("unroll")                                                          \
    for (int c_ = 0; c_ < 2; ++c_) {                                           \
      const int d_ = wv * 16 + c_ * 8 + (l >> 3);                              \
      const int cg_ = (l & 7) ^ (d_ & 7);                                      \
      const unsigned short* gsrc_ = inTb + (size_t)d_ * Nn + (kt) * 64 + cg_ * 8; \
      __builtin_amdgcn_global_load_lds(                                        \
          (const __attribute__((address_space(1))) void*)gsrc_,                \
          (__attribute__((address_space(3))) void*)(smc + (cur) * 16384 +      \
                                                   wv * 2048 + c_ * 1024),     \
          16, 0, 0);                                                           \
    }                                                                          \
  } while (0)

#define COMPUTE(ab, cur) do {                                                  \
    const char* Bbase = smc + (cur) * 16384;                                   \
    _Pragma("unroll")                                                          \
    for (int kc = 0; kc < 2; ++kc) {                                           \
      int4v ai0 = ab[kc * 2];                                                  \
      int4v ai1 = ab[kc * 2 + 1];                                              \
      dsum += ai0[0] + ai0[1] + ai0[2] + ai0[3] +                              \
              ai1[0] + ai1[1] + ai1[2] + ai1[3];                               \
      uint4v aw;                                                               \
      aw[0] = (unsigned)ai0[0] * 0x3F80u + (unsigned)ai0[1] * 0x3F800000u;     \
      aw[1] = (unsigned)ai0[2] * 0x3F80u + (unsigned)ai0[3] * 0x3F800000u;     \
      aw[2] = (unsigned)ai1[0] * 0x3F80u + (unsigned)ai1[1] * 0x3F800000u;     \
      aw[3] = (unsigned)ai1[2] * 0x3F80u + (unsigned)ai1[3] * 0x3F800000u;     \
      bf16x8 af = __builtin_bit_cast(bf16x8, aw);                              \
      _Pragma("unroll")                                                        \
      for (int cf = 0; cf < 4; ++cf) {                                         \
        const int brow_ = ch * 64 + cf * 16 + lr;                              \
        bf16x8 bfm = *(const bf16x8*)(Bbase + (size_t)brow_ * 128 +            \
                                      (((kc * 4 + lg) ^ swz8) * 16));          \
        acc[cf] = __builtin_amdgcn_mfma_f32_16x16x32_bf16(af, bfm, acc[cf],    \
                                                          0, 0, 0);            \
      }                                                                        \
    }                                                                          \
  } while (0)

#define WAITBAR(N) do {                                                        \
    asm volatile("s_waitcnt vmcnt(" #N ")" ::: "memory");                      \
    __builtin_amdgcn_s_barrier();                                              \
    __builtin_amdgcn_sched_barrier(0);                                         \
  } while (0)

__global__ __launch_bounds__(512, 2) void gcn_main(
    const float* __restrict__ input_, const int* __restrict__ adj,
    const float* __restrict__ bvec, const unsigned short* __restrict__ inT,
    const unsigned short* __restrict__ WT, float* __restrict__ out) {
  __shared__ SMem sm;
  char* smc = (char*)&sm;
  const int tid = threadIdx.x;
  const int wv = tid >> 6;                       // 0..7
  const int l = tid & 63, lr = l & 15, lg = (l >> 4) & 3;
  const int rg = wv >> 1, ch = wv & 1;           // 16 rows x 64 cols per wave

  // bijective XCD swizzle: 256 blocks (%8==0) -> XCD x gets batch x
  const int swz = (blockIdx.x & 7) * 32 + (blockIdx.x >> 3);
  const int bb = swz >> 5;
  const int row0 = (swz & 31) * 64;
  const int grow0 = bb * Nn + row0;

  const unsigned short* inTb = inT + (size_t)bb * Dn * Nn;

  // per-lane A stream base: row rg*16+lr, int offset lg*8 (A-frag k-layout)
  const int* pA = adj + (size_t)(grow0 + rg * 16 + lr) * Nn + lg * 8;

  const int swz8 = lr & 7;                       // B frag-read swizzle (row&7)
  f32x4 acc[4] = {};
  int dsum = 0;

  int4v aT0[4], aT1[4], aT2[4];                  // 3-deep A register tiles

  // prologue: tiles 0,1 staged (12 vmem ops in flight)
  STAGE(aT0, 0, 0);
  STAGE(aT1, 1, 1);

  #pragma unroll 1
  for (int j = 0; j < 10; ++j) {
    const int kt = 3 * j;
    WAITBAR(6); STAGE(aT2, 2, kt + 2); COMPUTE(aT0, 0);
    WAITBAR(6); STAGE(aT0, 0, kt + 3); COMPUTE(aT1, 1);
    WAITBAR(6); STAGE(aT1, 1, kt + 4); COMPUTE(aT2, 2);
  }
  // peel kt=30 (slot 0), kt=31 (slot 1); no further stages
  WAITBAR(6); COMPUTE(aT0, 0);
  WAITBAR(0); COMPUTE(aT1, 1);

  __syncthreads();                               // close K-loop: sm re-used below

  // ---- degree (adj in {0,1}: dsum is the partial row sum; ch-waves dup) ----
  {
    int s = dsum;
    s += __shfl_xor(s, 16);
    s += __shfl_xor(s, 32);                      // lanes lr,+16,+32,+48 summed
    if (l < 16) sm.e.degs[rg * 16 + l] = (s == 0) ? 1.0f : (float)s;
  }
  __syncthreads();

  // ---- agg = acc/deg staged as bf16 for GEMM2 ----
  float dgi[4];
  #pragma unroll
  for (int reg = 0; reg < 4; ++reg)
    dgi[reg] = 1.0f / sm.e.degs[rg * 16 + lg * 4 + reg];
  #pragma unroll
  for (int cf = 0; cf < 4; ++cf)
    #pragma unroll
    for (int reg = 0; reg < 4; ++reg)
      sm.e.aggl[rg * 16 + lg * 4 + reg][ch * 64 + cf * 16 + lr] =
          f2bf(acc[cf][reg] * dgi[reg]);
  __syncthreads();

  // ---- GEMM2: [x | agg] @ W (K=256); x direct from input_, B from WT ----
  f32x4 acc2[4] = {};
  const float* xrow = input_ + (size_t)(grow0 + rg * 16 + lr) * Dn;
  #pragma unroll
  for (int ks = 0; ks < 8; ++ks) {
    bf16x8 af;
    if (ks < 4) {
      float4v f0 = *(const float4v*)(xrow + ks * 32 + lg * 8);
      float4v f1 = *(const float4v*)(xrow + ks * 32 + lg * 8 + 4);
      ushort8 vv;
      #pragma unroll
      for (int e = 0; e < 4; ++e) { vv[e] = f2bf(f0[e]); vv[e + 4] = f2bf(f1[e]); }
      af = __builtin_bit_cast(bf16x8, vv);
    } else {
      af = *(const bf16x8*)&sm.e.aggl[rg * 16 + lr][(ks - 4) * 32 + lg * 8];
    }
    #pragma unroll
    for (int cf = 0; cf < 4; ++cf) {
      bf16x8 bw = *(const bf16x8*)(WT + (size_t)(ch * 64 + cf * 16 + lr) * 256 +
                                   ks * 32 + lg * 8);
      acc2[cf] = __builtin_amdgcn_mfma_f32_16x16x32_bf16(af, bw, acc2[cf], 0, 0, 0);
    }
  }

  // ---- bias + sigmoid + row L2-norm + store ----
  float bcol[4];
  #pragma unroll
  for (int cf = 0; cf < 4; ++cf) bcol[cf] = bvec[ch * 64 + cf * 16 + lr];
  float sg[4][4];
  #pragma unroll
  for (int cf = 0; cf < 4; ++cf)
    #pragma unroll
    for (int reg = 0; reg < 4; ++reg) {
      float x = acc2[cf][reg] + bcol[cf];
      sg[cf][reg] = 1.0f / (1.0f + expf(-x));
    }
  #pragma unroll
  for (int reg = 0; reg < 4; ++reg) {
    float p = 0.f;
    #pragma unroll
    for (int cf = 0; cf < 4; ++cf) p += sg[cf][reg] * sg[cf][reg];
    p += __shfl_xor(p, 1);
    p += __shfl_xor(p, 2);
    p += __shfl_xor(p, 4);
    p += __shfl_xor(p, 8);
    if (lr == 0) sm.e.rowsum[rg * 16 + lg * 4 + reg][ch] = p;
  }
  __syncthreads();
  #pragma unroll
  for (int reg = 0; reg < 4; ++reg) {
    const int row = rg * 16 + lg * 4 + reg;
    float nrm = rsqrtf(sm.e.rowsum[row][0] + sm.e.rowsum[row][1]);
    #pragma unroll
    for (int cf = 0; cf < 4; ++cf)
      out[(size_t)(grow0 + row) * OUTn + ch * 64 + cf * 16 + lr] =
          sg[cf][reg] * nrm;
  }
}

extern "C" void kernel_launch(void* const* d_in, const int* in_sizes, int n_in,
                              void* d_out, int out_size, void* d_ws, size_t ws_size,
                              hipStream_t stream) {
  (void)in_sizes; (void)n_in; (void)out_size; (void)ws_size;
  const float* input_ = (const float*)d_in[0];
  const int* adj = (const int*)d_in[1];
  const float* W = (const float*)d_in[2];
  const float* bvec = (const float*)d_in[3];
  float* out = (float*)d_out;

  unsigned short* inT = (unsigned short*)d_ws;                 // 4 MB
  unsigned short* WT = inT + (size_t)Bn * Dn * Nn;             // 64 KB

  hipLaunchKernelGGL(gcn_prep, dim3(384), dim3(256), 0, stream, input_, W, inT, WT);
  hipLaunchKernelGGL(gcn_main, dim3(256), dim3(512), 0, stream,
                     input_, adj, bvec, inT, WT, out);
}

// Round 15
// 56.957 us; speedup vs baseline: 1.0954x; 1.0954x over previous
//
#include <hip/hip_runtime.h>

#define Bn 8
#define Nn 2048
#define Dn 128
#define OUTn 128

typedef __attribute__((ext_vector_type(8))) short bf16x8;     // MFMA A/B operand (8 bf16)
typedef __attribute__((ext_vector_type(8))) unsigned short ushort8;
typedef __attribute__((ext_vector_type(4))) float f32x4;      // MFMA C/D
typedef __attribute__((ext_vector_type(4))) float float4v;

__device__ __forceinline__ unsigned short f2bf(float f) {
  unsigned int u = __builtin_bit_cast(unsigned int, f);
  u += 0x7FFFu + ((u >> 16) & 1u);   // round-to-nearest-even
  return (unsigned short)(u >> 16);
}

// ======== K1 (verified in R5): pack adj->bits+degree; transpose input; WT ========
// blocks [0,4096): pack (1 wave = 1 adjacency row, lane-contiguous streaming,
//                  free-running: no barriers, no LDS -> fill-kernel-class BW)
// blocks [4096,4352): input [b][n][d] fp32 -> inT [b][d][n] bf16
// blocks [4352,4480): W [2D][OUT] fp32 -> WT [OUT][2D] bf16
__global__ __launch_bounds__(256) void gcn_prep(
    const float* __restrict__ in, const int* __restrict__ adj,
    const float* __restrict__ W, unsigned long long* __restrict__ adjP,
    float* __restrict__ deg, unsigned short* __restrict__ inT,
    unsigned short* __restrict__ WT) {
  __shared__ __attribute__((aligned(16))) unsigned short lds[64][130];
  const int tid = threadIdx.x;
  const int bid = blockIdx.x;

  if (bid < 4096) {
    const int wv = tid >> 6, l = tid & 63;
    const int row = bid * 4 + wv;                 // 0..16383 == b*N + n
    const int* rp = adj + (size_t)row * Nn;
    int v[32];
    #pragma unroll
    for (int k = 0; k < 32; ++k) v[k] = rp[k * 64 + l];   // lane-contiguous 256B/instr
    unsigned long long myw = 0;
    int cnt = 0;
    #pragma unroll
    for (int k = 0; k < 32; ++k) {
      unsigned long long w = __ballot(v[k] != 0);  // bit l == col k*64+l
      cnt += __popcll(w);                          // wave-uniform
      if (l == k) myw = w;
    }
    if (l < 32) adjP[(size_t)row * 32 + l] = myw;
    if (l == 0) deg[row] = (cnt == 0) ? 1.0f : (float)cnt;
    return;
  }
  if (bid < 4352) {
    const int b = (bid - 4096) >> 5;
    const int n0 = ((bid - 4096) & 31) * 64;
    #pragma unroll
    for (int c = 0; c < 32; ++c) {
      int e = tid + c * 256;
      int i = e >> 7, d = e & 127;
      lds[i][d] = f2bf(in[((size_t)(b * Nn + n0 + i)) * Dn + d]);
    }
    __syncthreads();
    #pragma unroll
    for (int c = 0; c < 4; ++c) {
      int ch = tid + c * 256;
      int d = ch >> 3, g = (ch & 7) * 8;
      ushort8 vv;
      #pragma unroll
      for (int e = 0; e < 8; ++e) vv[e] = lds[g + e][d];
      *(ushort8*)(inT + ((size_t)(b * Dn + d)) * Nn + n0 + g) = vv;
    }
    return;
  }
  int gid = (bid - 4352) * 256 + tid;              // 0..32767
  int j = gid >> 8, k = gid & 255;                 // WT[j][k] = W[k][j]
  WT[gid] = f2bf(W[k * OUTn + j]);
}

// ======== K2: GEMM from packed bits, all-L2 K-loop ========
// 256 blocks x 512 threads (8 waves). Block = 64 rows of one batch, BK=64.
// A = bit-matrix (64 rows x 32 u64), staged ONCE into padded LDS (plain
// loads + one sync; 512 KB/batch, XCD-L2-resident). K-loop stages ONLY B
// (16 KB/tile, L2-hot inT) via the validated 3-buffer counted-vmcnt DMA:
// WAITBAR(2) = tile kt landed, kt+1's 2 loads/wave in flight, never drained.
// A expanded bits->bf16 at consume (~34 VALU/iter). Degree from pack's deg[].
union SMem {
  struct {
    unsigned long long A[64][33];      // 16896 B (pad 33: 16 rows -> 16 bank-pairs)
    unsigned short Bs[3][128][64];     // 49152 B (swizzled content, linear layout)
  } s;                                 // 66048 B -> 1-2 blocks/CU
  struct {
    unsigned short aggl[64][136];      // bf16 agg for GEMM2 A-frags
    float rowsum[64][2];
  } e;
};

#define STAGE(cur, kt) do {                                                    \
    _Pragma("unroll")                                                          \
    for (int c_ = 0; c_ < 2; ++c_) {                                           \
      const int d_ = wv * 16 + c_ * 8 + (l >> 3);                              \
      const int cg_ = (l & 7) ^ (d_ & 7);                                      \
      const unsigned short* gsrc_ = inTb + (size_t)d_ * Nn + (kt) * 64 + cg_ * 8; \
      __builtin_amdgcn_global_load_lds(                                        \
          (const __attribute__((address_space(1))) void*)gsrc_,                \
          (__attribute__((address_space(3))) void*)(smc + 16896 +              \
                                                   (cur) * 16384 +             \
                                                   wv * 2048 + c_ * 1024),     \
          16, 0, 0);                                                           \
    }                                                                          \
  } while (0)

#define COMPUTE(cur, kt) do {                                                  \
    const char* Bbase = smc + 16896 + (cur) * 16384;                           \
    const unsigned long long aw_ = sm.s.A[rg * 16 + lr][kt];                   \
    _Pragma("unroll")                                                          \
    for (int kc = 0; kc < 2; ++kc) {                                           \
      unsigned int bits = (unsigned int)(aw_ >> (kc * 32 + lg * 8)) & 0xFFu;   \
      ushort8 av;                                                              \
      _Pragma("unroll")                                                        \
      for (int e = 0; e < 8; ++e)                                              \
        av[e] = (bits & (1u << e)) ? (unsigned short)0x3F80u                   \
                                   : (unsigned short)0u;                       \
      bf16x8 af = __builtin_bit_cast(bf16x8, av);                              \
      _Pragma("unroll")                                                        \
      for (int cf = 0; cf < 4; ++cf) {                                         \
        const int brow_ = ch * 64 + cf * 16 + lr;                              \
        bf16x8 bfm = *(const bf16x8*)(Bbase + (size_t)brow_ * 128 +            \
                                      (((kc * 4 + lg) ^ swz8) * 16));          \
        acc[cf] = __builtin_amdgcn_mfma_f32_16x16x32_bf16(af, bfm, acc[cf],    \
                                                          0, 0, 0);            \
      }                                                                        \
    }                                                                          \
  } while (0)

#define WAITBAR(N) do {                                                        \
    asm volatile("s_waitcnt vmcnt(" #N ")" ::: "memory");                      \
    __builtin_amdgcn_s_barrier();                                              \
    __builtin_amdgcn_sched_barrier(0);                                         \
  } while (0)

__global__ __launch_bounds__(512, 2) void gcn_main(
    const float* __restrict__ input_, const unsigned long long* __restrict__ adjP,
    const float* __restrict__ deg, const float* __restrict__ bvec,
    const unsigned short* __restrict__ inT, const unsigned short* __restrict__ WT,
    float* __restrict__ out) {
  __shared__ SMem sm;
  char* smc = (char*)&sm;
  const int tid = threadIdx.x;
  const int wv = tid >> 6;                       // 0..7
  const int l = tid & 63, lr = l & 15, lg = (l >> 4) & 3;
  const int rg = wv >> 1, ch = wv & 1;           // 16 rows x 64 cols per wave

  // bijective XCD swizzle: 256 blocks (%8==0) -> XCD x gets batch x
  const int swz = (blockIdx.x & 7) * 32 + (blockIdx.x >> 3);
  const int bb = swz >> 5;
  const int row0 = (swz & 31) * 64;
  const int grow0 = bb * Nn + row0;

  const unsigned short* inTb = inT + (size_t)bb * Dn * Nn;
  const int swz8 = lr & 7;                       // B frag-read swizzle (row&7)
  f32x4 acc[4] = {};

  // ---- stage A bits once: 64 rows x 32 u64 -> padded LDS ----
  {
    const unsigned long long* src = adjP + (size_t)grow0 * 32 + tid * 4;
    #pragma unroll
    for (int j = 0; j < 4; ++j) {
      int idx = tid * 4 + j;
      sm.s.A[idx >> 5][idx & 31] = src[j];
    }
  }
  __syncthreads();

  // prologue: B tiles 0,1 staged (4 loads/wave in flight)
  STAGE(0, 0);
  STAGE(1, 1);

  #pragma unroll 1
  for (int j = 0; j < 10; ++j) {
    const int kt = 3 * j;
    WAITBAR(2); STAGE(2, kt + 2); COMPUTE(0, kt);
    WAITBAR(2); STAGE(0, kt + 3); COMPUTE(1, kt + 1);
    WAITBAR(2); STAGE(1, kt + 4); COMPUTE(2, kt + 2);
  }
  // peel kt=30 (buf0), kt=31 (buf1); no further stages
  WAITBAR(2); COMPUTE(0, 30);
  WAITBAR(0); COMPUTE(1, 31);

  __syncthreads();                               // close K-loop: sm re-used below

  // ---- agg = acc/deg staged as bf16 for GEMM2 (deg from pack pass) ----
  float dgi[4];
  #pragma unroll
  for (int reg = 0; reg < 4; ++reg)
    dgi[reg] = 1.0f / deg[grow0 + rg * 16 + lg * 4 + reg];
  #pragma unroll
  for (int cf = 0; cf < 4; ++cf)
    #pragma unroll
    for (int reg = 0; reg < 4; ++reg)
      sm.e.aggl[rg * 16 + lg * 4 + reg][ch * 64 + cf * 16 + lr] =
          f2bf(acc[cf][reg] * dgi[reg]);
  __syncthreads();

  // ---- GEMM2: [x | agg] @ W (K=256); x direct from input_, B from WT ----
  f32x4 acc2[4] = {};
  const float* xrow = input_ + (size_t)(grow0 + rg * 16 + lr) * Dn;
  #pragma unroll
  for (int ks = 0; ks < 8; ++ks) {
    bf16x8 af;
    if (ks < 4) {
      float4v f0 = *(const float4v*)(xrow + ks * 32 + lg * 8);
      float4v f1 = *(const float4v*)(xrow + ks * 32 + lg * 8 + 4);
      ushort8 vv;
      #pragma unroll
      for (int e = 0; e < 4; ++e) { vv[e] = f2bf(f0[e]); vv[e + 4] = f2bf(f1[e]); }
      af = __builtin_bit_cast(bf16x8, vv);
    } else {
      af = *(const bf16x8*)&sm.e.aggl[rg * 16 + lr][(ks - 4) * 32 + lg * 8];
    }
    #pragma unroll
    for (int cf = 0; cf < 4; ++cf) {
      bf16x8 bw = *(const bf16x8*)(WT + (size_t)(ch * 64 + cf * 16 + lr) * 256 +
                                   ks * 32 + lg * 8);
      acc2[cf] = __builtin_amdgcn_mfma_f32_16x16x32_bf16(af, bw, acc2[cf], 0, 0, 0);
    }
  }

  // ---- bias + sigmoid + row L2-norm + store ----
  float bcol[4];
  #pragma unroll
  for (int cf = 0; cf < 4; ++cf) bcol[cf] = bvec[ch * 64 + cf * 16 + lr];
  float sg[4][4];
  #pragma unroll
  for (int cf = 0; cf < 4; ++cf)
    #pragma unroll
    for (int reg = 0; reg < 4; ++reg) {
      float x = acc2[cf][reg] + bcol[cf];
      sg[cf][reg] = 1.0f / (1.0f + expf(-x));
    }
  #pragma unroll
  for (int reg = 0; reg < 4; ++reg) {
    float p = 0.f;
    #pragma unroll
    for (int cf = 0; cf < 4; ++cf) p += sg[cf][reg] * sg[cf][reg];
    p += __shfl_xor(p, 1);
    p += __shfl_xor(p, 2);
    p += __shfl_xor(p, 4);
    p += __shfl_xor(p, 8);
    if (lr == 0) sm.e.rowsum[rg * 16 + lg * 4 + reg][ch] = p;
  }
  __syncthreads();
  #pragma unroll
  for (int reg = 0; reg < 4; ++reg) {
    const int row = rg * 16 + lg * 4 + reg;
    float nrm = rsqrtf(sm.e.rowsum[row][0] + sm.e.rowsum[row][1]);
    #pragma unroll
    for (int cf = 0; cf < 4; ++cf)
      out[(size_t)(grow0 + row) * OUTn + ch * 64 + cf * 16 + lr] =
          sg[cf][reg] * nrm;
  }
}

extern "C" void kernel_launch(void* const* d_in, const int* in_sizes, int n_in,
                              void* d_out, int out_size, void* d_ws, size_t ws_size,
                              hipStream_t stream) {
  (void)in_sizes; (void)n_in; (void)out_size; (void)ws_size;
  const float* input_ = (const float*)d_in[0];
  const int* adj = (const int*)d_in[1];
  const float* W = (const float*)d_in[2];
  const float* bvec = (const float*)d_in[3];
  float* out = (float*)d_out;

  // workspace layout (8.25 MB total):
  unsigned short* inT = (unsigned short*)d_ws;                          // 4 MB
  unsigned short* WT = inT + (size_t)Bn * Dn * Nn;                      // 64 KB
  unsigned long long* adjP =
      (unsigned long long*)((char*)d_ws + 4194304 + 65536);             // 4 MB
  float* deg = (float*)((char*)d_ws + 4194304 + 65536 + 4194304);       // 64 KB

  hipLaunchKernelGGL(gcn_prep, dim3(4480), dim3(256), 0, stream,
                     input_, adj, W, adjP, deg, inT, WT);
  hipLaunchKernelGGL(gcn_main, dim3(256), dim3(512), 0, stream,
                     input_, adjP, deg, bvec, inT, WT, out);
}

// Round 16
// 49.431 us; speedup vs baseline: 1.2621x; 1.1522x over previous
//
#include <hip/hip_runtime.h>

#define Bn 8
#define Nn 2048
#define Dn 128
#define OUTn 128

typedef __attribute__((ext_vector_type(8))) short bf16x8;     // MFMA A/B operand (8 bf16)
typedef __attribute__((ext_vector_type(8))) unsigned short ushort8;
typedef __attribute__((ext_vector_type(4))) float f32x4;      // MFMA C/D
typedef __attribute__((ext_vector_type(4))) int int4v;
typedef __attribute__((ext_vector_type(4))) unsigned int uint4v;
typedef __attribute__((ext_vector_type(4))) float float4v;

__device__ __forceinline__ unsigned short f2bf(float f) {
  unsigned int u = __builtin_bit_cast(unsigned int, f);
  u += 0x7FFFu + ((u >> 16) & 1u);   // round-to-nearest-even
  return (unsigned short)(u >> 16);
}

// ---------------- prep: transpose input + transpose W ----------------
__global__ __launch_bounds__(256) void gcn_prep(const float* __restrict__ in,
                                                const float* __restrict__ W,
                                                unsigned short* __restrict__ inT,
                                                unsigned short* __restrict__ WT) {
  const int tid = threadIdx.x;
  if (blockIdx.x >= 256) {
    int gid = (blockIdx.x - 256) * 256 + tid;    // 0..32767
    int j = gid >> 8, k = gid & 255;             // WT[j][k] = W[k][j]
    WT[gid] = f2bf(W[k * OUTn + j]);
    return;
  }
  const int b = blockIdx.x >> 5;
  const int n0 = (blockIdx.x & 31) * 64;
  __shared__ __attribute__((aligned(16))) unsigned short lds[64][130];
  #pragma unroll
  for (int c = 0; c < 32; ++c) {
    int e = tid + c * 256;
    int i = e >> 7, d = e & 127;
    lds[i][d] = f2bf(in[((size_t)(b * Nn + n0 + i)) * Dn + d]);
  }
  __syncthreads();
  #pragma unroll
  for (int c = 0; c < 4; ++c) {
    int ch = tid + c * 256;
    int d = ch >> 3, g = (ch & 7) * 8;
    ushort8 v;
    #pragma unroll
    for (int e = 0; e < 8; ++e) v[e] = lds[g + e][d];
    *(ushort8*)(inT + ((size_t)(b * Dn + d)) * Nn + n0 + g) = v;
  }
}

// ---------------- main: BK=128, 16 iterations, 2-buf DMA, 1 barrier/iter -----
// 256 blocks x 512 threads (8 waves). Block = 64 rows of one batch, BK=128.
// Iteration count halved vs BK=64 (the measured ~1000cyc/iter fixed cost was
// 32K of R12's 84K cyc). 2-buffer depth-1: WAITBAR(0) is EXACT (only tile kt
// outstanding when waiting for it); tile kt+1's 8 loads issued right after
// the barrier fly under COMPUTE(kt)'s 16 MFMA + bit-expansion.
// A raw int32 in LDS, converted at frag-read (adj in {0,1}: bf16 = v*0x3F80).
// 16B-chunk XOR swizzle (chunk ^= row&7) on global source + ds_read (rule #21).
union SMem {
  struct {
    int A[2][64][128];                 // 64 KB (swizzled content, linear layout)
    unsigned short Bs[2][128][128];    // 64 KB
  } s;                                 // 128 KB -> 1 block/CU
  struct {
    unsigned short aggl[64][136];      // bf16 agg for GEMM2 A-frags
    float rowsum[64][2];
    float degs[64];
  } e;
};

#define STAGE(cur, kt) do {                                                    \
    _Pragma("unroll")                                                          \
    for (int c_ = 0; c_ < 4; ++c_) {                                           \
      const int r_ = c_ * 16 + wv * 2 + (l >> 5);                              \
      const int cg_ = (l & 31) ^ (r_ & 7);                                     \
      const int* gsrc_ = adjB + (size_t)r_ * Nn + (kt) * 128 + cg_ * 4;        \
      __builtin_amdgcn_global_load_lds(                                        \
          (const __attribute__((address_space(1))) void*)gsrc_,                \
          (__attribute__((address_space(3))) void*)(smc + (cur) * 32768 +      \
                                                   c_ * 8192 + wv * 1024),     \
          16, 0, 0);                                                           \
    }                                                                          \
    _Pragma("unroll")                                                          \
    for (int c_ = 0; c_ < 4; ++c_) {                                           \
      const int d_ = c_ * 32 + wv * 4 + (l >> 4);                              \
      const int cg_ = (l & 15) ^ (d_ & 7);                                     \
      const unsigned short* gsrc_ = inTb + (size_t)d_ * Nn + (kt) * 128 + cg_ * 8; \
      __builtin_amdgcn_global_load_lds(                                        \
          (const __attribute__((address_space(1))) void*)gsrc_,                \
          (__attribute__((address_space(3))) void*)(smc + 65536 +              \
                                                   (cur) * 32768 +             \
                                                   c_ * 8192 + wv * 1024),     \
          16, 0, 0);                                                           \
    }                                                                          \
  } while (0)

#define COMPUTE(cur) do {                                                      \
    const char* Abase = smc + (cur) * 32768 + (rg * 16 + lr) * 512;            \
    const char* Bbase = smc + 65536 + (cur) * 32768;                           \
    _Pragma("unroll")                                                          \
    for (int kc = 0; kc < 4; ++kc) {                                           \
      const int c0_ = kc * 8 + lg * 2;                                         \
      int4v ai0 = *(const int4v*)(Abase + ((c0_ ^ swz8) * 16));                \
      int4v ai1 = *(const int4v*)(Abase + (((c0_ + 1) ^ swz8) * 16));          \
      dsum += ai0[0] + ai0[1] + ai0[2] + ai0[3] +                              \
              ai1[0] + ai1[1] + ai1[2] + ai1[3];                               \
      uint4v aw;                                                               \
      aw[0] = (unsigned)ai0[0] * 0x3F80u + (unsigned)ai0[1] * 0x3F800000u;     \
      aw[1] = (unsigned)ai0[2] * 0x3F80u + (unsigned)ai0[3] * 0x3F800000u;     \
      aw[2] = (unsigned)ai1[0] * 0x3F80u + (unsigned)ai1[1] * 0x3F800000u;     \
      aw[3] = (unsigned)ai1[2] * 0x3F80u + (unsigned)ai1[3] * 0x3F800000u;     \
      bf16x8 af = __builtin_bit_cast(bf16x8, aw);                              \
      _Pragma("unroll")                                                        \
      for (int cf = 0; cf < 4; ++cf) {                                         \
        const int brow_ = ch * 64 + cf * 16 + lr;                              \
        bf16x8 bfm = *(const bf16x8*)(Bbase + (size_t)brow_ * 256 +            \
                                      (((kc * 4 + lg) ^ swz8) * 16));          \
        acc[cf] = __builtin_amdgcn_mfma_f32_16x16x32_bf16(af, bfm, acc[cf],    \
                                                          0, 0, 0);            \
      }                                                                        \
    }                                                                          \
  } while (0)

#define WAITBAR(N) do {                                                        \
    asm volatile("s_waitcnt vmcnt(" #N ")" ::: "memory");                      \
    __builtin_amdgcn_s_barrier();                                              \
    __builtin_amdgcn_sched_barrier(0);                                         \
  } while (0)

__global__ __launch_bounds__(512, 2) void gcn_main(
    const float* __restrict__ input_, const int* __restrict__ adj,
    const float* __restrict__ bvec, const unsigned short* __restrict__ inT,
    const unsigned short* __restrict__ WT, float* __restrict__ out) {
  __shared__ SMem sm;
  char* smc = (char*)&sm;
  const int tid = threadIdx.x;
  const int wv = tid >> 6;                       // 0..7
  const int l = tid & 63, lr = l & 15, lg = (l >> 4) & 3;
  const int rg = wv >> 1, ch = wv & 1;           // 16 rows x 64 cols per wave

  // bijective XCD swizzle: 256 blocks (%8==0) -> XCD x gets batch x
  const int swz = (blockIdx.x & 7) * 32 + (blockIdx.x >> 3);
  const int bb = swz >> 5;
  const int row0 = (swz & 31) * 64;
  const int grow0 = bb * Nn + row0;

  const int* adjB = adj + (size_t)grow0 * Nn;
  const unsigned short* inTb = inT + (size_t)bb * Dn * Nn;

  const int swz8 = lr & 7;                       // frag-read swizzle (row&7)
  f32x4 acc[4] = {};
  int dsum = 0;

  // prologue: tile 0 staged (8 loads/wave)
  STAGE(0, 0);

  #pragma unroll 1
  for (int j = 0; j < 8; ++j) {
    // even tile 2j in buf0
    WAITBAR(0);                       // exact: only tile 2j outstanding
    STAGE(1, 2 * j + 1);              // buf1 freed by the barrier (tile 2j-1 done)
    COMPUTE(0);
    // odd tile 2j+1 in buf1
    WAITBAR(0);
    if (j < 7) STAGE(0, 2 * j + 2);
    COMPUTE(1);
  }

  __syncthreads();                               // close K-loop: sm re-used below

  // ---- degree (adj in {0,1}: dsum is the partial row sum; ch-waves dup) ----
  {
    int s = dsum;
    s += __shfl_xor(s, 16);
    s += __shfl_xor(s, 32);                      // lanes lr,+16,+32,+48 summed
    if (l < 16) sm.e.degs[rg * 16 + l] = (s == 0) ? 1.0f : (float)s;
  }
  __syncthreads();

  // ---- agg = acc/deg staged as bf16 for GEMM2 ----
  float dgi[4];
  #pragma unroll
  for (int reg = 0; reg < 4; ++reg)
    dgi[reg] = 1.0f / sm.e.degs[rg * 16 + lg * 4 + reg];
  #pragma unroll
  for (int cf = 0; cf < 4; ++cf)
    #pragma unroll
    for (int reg = 0; reg < 4; ++reg)
      sm.e.aggl[rg * 16 + lg * 4 + reg][ch * 64 + cf * 16 + lr] =
          f2bf(acc[cf][reg] * dgi[reg]);
  __syncthreads();

  // ---- GEMM2: [x | agg] @ W (K=256); x direct from input_, B from WT ----
  f32x4 acc2[4] = {};
  const float* xrow = input_ + (size_t)(grow0 + rg * 16 + lr) * Dn;
  #pragma unroll
  for (int ks = 0; ks < 8; ++ks) {
    bf16x8 af;
    if (ks < 4) {
      float4v f0 = *(const float4v*)(xrow + ks * 32 + lg * 8);
      float4v f1 = *(const float4v*)(xrow + ks * 32 + lg * 8 + 4);
      ushort8 vv;
      #pragma unroll
      for (int e = 0; e < 4; ++e) { vv[e] = f2bf(f0[e]); vv[e + 4] = f2bf(f1[e]); }
      af = __builtin_bit_cast(bf16x8, vv);
    } else {
      af = *(const bf16x8*)&sm.e.aggl[rg * 16 + lr][(ks - 4) * 32 + lg * 8];
    }
    #pragma unroll
    for (int cf = 0; cf < 4; ++cf) {
      bf16x8 bw = *(const bf16x8*)(WT + (size_t)(ch * 64 + cf * 16 + lr) * 256 +
                                   ks * 32 + lg * 8);
      acc2[cf] = __builtin_amdgcn_mfma_f32_16x16x32_bf16(af, bw, acc2[cf], 0, 0, 0);
    }
  }

  // ---- bias + sigmoid + row L2-norm + store ----
  float bcol[4];
  #pragma unroll
  for (int cf = 0; cf < 4; ++cf) bcol[cf] = bvec[ch * 64 + cf * 16 + lr];
  float sg[4][4];
  #pragma unroll
  for (int cf = 0; cf < 4; ++cf)
    #pragma unroll
    for (int reg = 0; reg < 4; ++reg) {
      float x = acc2[cf][reg] + bcol[cf];
      sg[cf][reg] = 1.0f / (1.0f + expf(-x));
    }
  #pragma unroll
  for (int reg = 0; reg < 4; ++reg) {
    float p = 0.f;
    #pragma unroll
    for (int cf = 0; cf < 4; ++cf) p += sg[cf][reg] * sg[cf][reg];
    p += __shfl_xor(p, 1);
    p += __shfl_xor(p, 2);
    p += __shfl_xor(p, 4);
    p += __shfl_xor(p, 8);
    if (lr == 0) sm.e.rowsum[rg * 16 + lg * 4 + reg][ch] = p;
  }
  __syncthreads();
  #pragma unroll
  for (int reg = 0; reg < 4; ++reg) {
    const int row = rg * 16 + lg * 4 + reg;
    float nrm = rsqrtf(sm.e.rowsum[row][0] + sm.e.rowsum[row][1]);
    #pragma unroll
    for (int cf = 0; cf < 4; ++cf)
      out[(size_t)(grow0 + row) * OUTn + ch * 64 + cf * 16 + lr] =
          sg[cf][reg] * nrm;
  }
}

extern "C" void kernel_launch(void* const* d_in, const int* in_sizes, int n_in,
                              void* d_out, int out_size, void* d_ws, size_t ws_size,
                              hipStream_t stream) {
  (void)in_sizes; (void)n_in; (void)out_size; (void)ws_size;
  const float* input_ = (const float*)d_in[0];
  const int* adj = (const int*)d_in[1];
  const float* W = (const float*)d_in[2];
  const float* bvec = (const float*)d_in[3];
  float* out = (float*)d_out;

  unsigned short* inT = (unsigned short*)d_ws;                 // 4 MB
  unsigned short* WT = inT + (size_t)Bn * Dn * Nn;             // 64 KB

  hipLaunchKernelGGL(gcn_prep, dim3(384), dim3(256), 0, stream, input_, W, inT, WT);
  hipLaunchKernelGGL(gcn_main, dim3(256), dim3(512), 0, stream,
                     input_, adj, bvec, inT, WT, out);
}

// Round 17
// 43.028 us; speedup vs baseline: 1.4500x; 1.1488x over previous
//
#include <hip/hip_runtime.h>

#define Bn 8
#define Nn 2048
#define Dn 128
#define OUTn 128

typedef __attribute__((ext_vector_type(8))) short bf16x8;     // MFMA A/B operand (8 bf16)
typedef __attribute__((ext_vector_type(8))) unsigned short ushort8;
typedef __attribute__((ext_vector_type(4))) float f32x4;      // MFMA C/D
typedef __attribute__((ext_vector_type(4))) int int4v;
typedef __attribute__((ext_vector_type(4))) unsigned int uint4v;
typedef __attribute__((ext_vector_type(4))) float float4v;

__device__ __forceinline__ unsigned short f2bf(float f) {
  unsigned int u = __builtin_bit_cast(unsigned int, f);
  u += 0x7FFFu + ((u >> 16) & 1u);   // round-to-nearest-even
  return (unsigned short)(u >> 16);
}

// ---------------- prep: transpose input + transpose W ----------------
__global__ __launch_bounds__(256) void gcn_prep(const float* __restrict__ in,
                                                const float* __restrict__ W,
                                                unsigned short* __restrict__ inT,
                                                unsigned short* __restrict__ WT) {
  const int tid = threadIdx.x;
  if (blockIdx.x >= 256) {
    int gid = (blockIdx.x - 256) * 256 + tid;    // 0..32767
    int j = gid >> 8, k = gid & 255;             // WT[j][k] = W[k][j]
    WT[gid] = f2bf(W[k * OUTn + j]);
    return;
  }
  const int b = blockIdx.x >> 5;
  const int n0 = (blockIdx.x & 31) * 64;
  __shared__ __attribute__((aligned(16))) unsigned short lds[64][130];
  #pragma unroll
  for (int c = 0; c < 32; ++c) {
    int e = tid + c * 256;
    int i = e >> 7, d = e & 127;
    lds[i][d] = f2bf(in[((size_t)(b * Nn + n0 + i)) * Dn + d]);
  }
  __syncthreads();
  #pragma unroll
  for (int c = 0; c < 4; ++c) {
    int ch = tid + c * 256;
    int d = ch >> 3, g = (ch & 7) * 8;
    ushort8 v;
    #pragma unroll
    for (int e = 0; e < 8; ++e) v[e] = lds[g + e][d];
    *(ushort8*)(inT + ((size_t)(b * Dn + d)) * Nn + n0 + g) = v;
  }
}

// ---------------- main: R12 structure + 4th buffer (depth-2 slack) ----------
// 256 blocks x 512 threads (8 waves). Block = 64 rows of one batch, BK=64.
// Pure depth ablation vs R12 (42.5us): same tiles, same schedule shape, same
// swizzles/epilogue; 4 LDS buffers and WAITBAR(8) so tiles kt+1 AND kt+2
// (8 loads/wave) stay in flight through every COMPUTE — 2 iterations (~5200
// cyc) of straggler slack vs R12's one. LDS 128 KB -> 1 block/CU.
// A raw int32 in LDS, converted at frag-read (adj in {0,1}: bf16 = v*0x3F80).
// 16B-chunk XOR swizzle (chunk ^= row&7) on global source + ds_read (rule #21).
union SMem {
  struct {
    int A[4][64][64];                  // 64 KB (swizzled content, linear layout)
    unsigned short Bs[4][128][64];     // 64 KB
  } s;                                 // 128 KB -> 1 block/CU
  struct {
    unsigned short aggl[64][136];      // bf16 agg for GEMM2 A-frags
    float rowsum[64][2];
    float degs[64];
  } e;
};

#define STAGE(cur, kt) do {                                                    \
    _Pragma("unroll")                                                          \
    for (int c_ = 0; c_ < 2; ++c_) {                                           \
      const int r_ = wv * 8 + c_ * 4 + (l >> 4);                               \
      const int cg_ = (l & 15) ^ (r_ & 7);                                     \
      const int* gsrc_ = adjB + (size_t)r_ * Nn + (kt) * 64 + cg_ * 4;         \
      __builtin_amdgcn_global_load_lds(                                        \
          (const __attribute__((address_space(1))) void*)gsrc_,                \
          (__attribute__((address_space(3))) void*)(smc + (cur) * 16384 +      \
                                                   wv * 2048 + c_ * 1024),     \
          16, 0, 0);                                                           \
    }                                                                          \
    _Pragma("unroll")                                                          \
    for (int c_ = 0; c_ < 2; ++c_) {                                           \
      const int d_ = wv * 16 + c_ * 8 + (l >> 3);                              \
      const int cg_ = (l & 7) ^ (d_ & 7);                                      \
      const unsigned short* gsrc_ = inTb + (size_t)d_ * Nn + (kt) * 64 + cg_ * 8; \
      __builtin_amdgcn_global_load_lds(                                        \
          (const __attribute__((address_space(1))) void*)gsrc_,                \
          (__attribute__((address_space(3))) void*)(smc + 65536 +              \
                                                   (cur) * 16384 +             \
                                                   wv * 2048 + c_ * 1024),     \
          16, 0, 0);                                                           \
    }                                                                          \
  } while (0)

#define COMPUTE(cur) do {                                                      \
    const char* Abase = smc + (cur) * 16384 + (rg * 16 + lr) * 256;            \
    const char* Bbase = smc + 65536 + (cur) * 16384;                           \
    _Pragma("unroll")                                                          \
    for (int kc = 0; kc < 2; ++kc) {                                           \
      const int c0_ = kc * 8 + lg * 2;                                         \
      int4v ai0 = *(const int4v*)(Abase + ((c0_ ^ swz8) * 16));                \
      int4v ai1 = *(const int4v*)(Abase + (((c0_ + 1) ^ swz8) * 16));          \
      dsum += ai0[0] + ai0[1] + ai0[2] + ai0[3] +                              \
              ai1[0] + ai1[1] + ai1[2] + ai1[3];                               \
      uint4v aw;                                                               \
      aw[0] = (unsigned)ai0[0] * 0x3F80u + (unsigned)ai0[1] * 0x3F800000u;     \
      aw[1] = (unsigned)ai0[2] * 0x3F80u + (unsigned)ai0[3] * 0x3F800000u;     \
      aw[2] = (unsigned)ai1[0] * 0x3F80u + (unsigned)ai1[1] * 0x3F800000u;     \
      aw[3] = (unsigned)ai1[2] * 0x3F80u + (unsigned)ai1[3] * 0x3F800000u;     \
      bf16x8 af = __builtin_bit_cast(bf16x8, aw);                              \
      _Pragma("unroll")                                                        \
      for (int cf = 0; cf < 4; ++cf) {                                         \
        const int brow_ = ch * 64 + cf * 16 + lr;                              \
        bf16x8 bfm = *(const bf16x8*)(Bbase + (size_t)brow_ * 128 +            \
                                      (((kc * 4 + lg) ^ swz8) * 16));          \
        acc[cf] = __builtin_amdgcn_mfma_f32_16x16x32_bf16(af, bfm, acc[cf],    \
                                                          0, 0, 0);            \
      }                                                                        \
    }                                                                          \
  } while (0)

#define WAITBAR(N) do {                                                        \
    asm volatile("s_waitcnt vmcnt(" #N ")" ::: "memory");                      \
    __builtin_amdgcn_s_barrier();                                              \
    __builtin_amdgcn_sched_barrier(0);                                         \
  } while (0)

__global__ __launch_bounds__(512, 2) void gcn_main(
    const float* __restrict__ input_, const int* __restrict__ adj,
    const float* __restrict__ bvec, const unsigned short* __restrict__ inT,
    const unsigned short* __restrict__ WT, float* __restrict__ out) {
  __shared__ SMem sm;
  char* smc = (char*)&sm;
  const int tid = threadIdx.x;
  const int wv = tid >> 6;                       // 0..7
  const int l = tid & 63, lr = l & 15, lg = (l >> 4) & 3;
  const int rg = wv >> 1, ch = wv & 1;           // 16 rows x 64 cols per wave

  // bijective XCD swizzle: 256 blocks (%8==0) -> XCD x gets batch x
  const int swz = (blockIdx.x & 7) * 32 + (blockIdx.x >> 3);
  const int bb = swz >> 5;
  const int row0 = (swz & 31) * 64;
  const int grow0 = bb * Nn + row0;

  const int* adjB = adj + (size_t)grow0 * Nn;
  const unsigned short* inTb = inT + (size_t)bb * Dn * Nn;

  const int swz8 = lr & 7;                       // frag-read swizzle (row&7)
  f32x4 acc[4] = {};
  int dsum = 0;

  // prologue: tiles 0,1,2 staged (12 loads/wave in flight)
  STAGE(0, 0);
  STAGE(1, 1);
  STAGE(2, 2);

  #pragma unroll 1
  for (int j = 0; j < 7; ++j) {
    const int kt = 4 * j;
    WAITBAR(8); STAGE(3, kt + 3); COMPUTE(0);
    WAITBAR(8); STAGE(0, kt + 4); COMPUTE(1);
    WAITBAR(8); STAGE(1, kt + 5); COMPUTE(2);
    WAITBAR(8); STAGE(2, kt + 6); COMPUTE(3);
  }
  // peel kt=28..31 (stage 31 at kt=28; then drain 8->4->0)
  WAITBAR(8); STAGE(3, 31); COMPUTE(0);
  WAITBAR(8); COMPUTE(1);
  WAITBAR(4); COMPUTE(2);
  WAITBAR(0); COMPUTE(3);

  __syncthreads();                               // close K-loop: sm re-used below

  // ---- degree (adj in {0,1}: dsum is the partial row sum; ch-waves dup) ----
  {
    int s = dsum;
    s += __shfl_xor(s, 16);
    s += __shfl_xor(s, 32);                      // lanes lr,+16,+32,+48 summed
    if (l < 16) sm.e.degs[rg * 16 + l] = (s == 0) ? 1.0f : (float)s;
  }
  __syncthreads();

  // ---- agg = acc/deg staged as bf16 for GEMM2 ----
  float dgi[4];
  #pragma unroll
  for (int reg = 0; reg < 4; ++reg)
    dgi[reg] = 1.0f / sm.e.degs[rg * 16 + lg * 4 + reg];
  #pragma unroll
  for (int cf = 0; cf < 4; ++cf)
    #pragma unroll
    for (int reg = 0; reg < 4; ++reg)
      sm.e.aggl[rg * 16 + lg * 4 + reg][ch * 64 + cf * 16 + lr] =
          f2bf(acc[cf][reg] * dgi[reg]);
  __syncthreads();

  // ---- GEMM2: [x | agg] @ W (K=256); x direct from input_, B from WT ----
  f32x4 acc2[4] = {};
  const float* xrow = input_ + (size_t)(grow0 + rg * 16 + lr) * Dn;
  #pragma unroll
  for (int ks = 0; ks < 8; ++ks) {
    bf16x8 af;
    if (ks < 4) {
      float4v f0 = *(const float4v*)(xrow + ks * 32 + lg * 8);
      float4v f1 = *(const float4v*)(xrow + ks * 32 + lg * 8 + 4);
      ushort8 vv;
      #pragma unroll
      for (int e = 0; e < 4; ++e) { vv[e] = f2bf(f0[e]); vv[e + 4] = f2bf(f1[e]); }
      af = __builtin_bit_cast(bf16x8, vv);
    } else {
      af = *(const bf16x8*)&sm.e.aggl[rg * 16 + lr][(ks - 4) * 32 + lg * 8];
    }
    #pragma unroll
    for (int cf = 0; cf < 4; ++cf) {
      bf16x8 bw = *(const bf16x8*)(WT + (size_t)(ch * 64 + cf * 16 + lr) * 256 +
                                   ks * 32 + lg * 8);
      acc2[cf] = __builtin_amdgcn_mfma_f32_16x16x32_bf16(af, bw, acc2[cf], 0, 0, 0);
    }
  }

  // ---- bias + sigmoid + row L2-norm + store ----
  float bcol[4];
  #pragma unroll
  for (int cf = 0; cf < 4; ++cf) bcol[cf] = bvec[ch * 64 + cf * 16 + lr];
  float sg[4][4];
  #pragma unroll
  for (int cf = 0; cf < 4; ++cf)
    #pragma unroll
    for (int reg = 0; reg < 4; ++reg) {
      float x = acc2[cf][reg] + bcol[cf];
      sg[cf][reg] = 1.0f / (1.0f + expf(-x));
    }
  #pragma unroll
  for (int reg = 0; reg < 4; ++reg) {
    float p = 0.f;
    #pragma unroll
    for (int cf = 0; cf < 4; ++cf) p += sg[cf][reg] * sg[cf][reg];
    p += __shfl_xor(p, 1);
    p += __shfl_xor(p, 2);
    p += __shfl_xor(p, 4);
    p += __shfl_xor(p, 8);
    if (lr == 0) sm.e.rowsum[rg * 16 + lg * 4 + reg][ch] = p;
  }
  __syncthreads();
  #pragma unroll
  for (int reg = 0; reg < 4; ++reg) {
    const int row = rg * 16 + lg * 4 + reg;
    float nrm = rsqrtf(sm.e.rowsum[row][0] + sm.e.rowsum[row][1]);
    #pragma unroll
    for (int cf = 0; cf < 4; ++cf)
      out[(size_t)(grow0 + row) * OUTn + ch * 64 + cf * 16 + lr] =
          sg[cf][reg] * nrm;
  }
}

extern "C" void kernel_launch(void* const* d_in, const int* in_sizes, int n_in,
                              void* d_out, int out_size, void* d_ws, size_t ws_size,
                              hipStream_t stream) {
  (void)in_sizes; (void)n_in; (void)out_size; (void)ws_size;
  const float* input_ = (const float*)d_in[0];
  const int* adj = (const int*)d_in[1];
  const float* W = (const float*)d_in[2];
  const float* bvec = (const float*)d_in[3];
  float* out = (float*)d_out;

  unsigned short* inT = (unsigned short*)d_ws;                 // 4 MB
  unsigned short* WT = inT + (size_t)Bn * Dn * Nn;             // 64 KB

  hipLaunchKernelGGL(gcn_prep, dim3(384), dim3(256), 0, stream, input_, W, inT, WT);
  hipLaunchKernelGGL(gcn_main, dim3(256), dim3(512), 0, stream,
                     input_, adj, bvec, inT, WT, out);
}